// Round 6
// baseline (174.114 us; speedup 1.0000x reference)
//
#include <hip/hip_runtime.h>
#include <stdint.h>

#define BATCH   2048
#define KDIM    4096
#define NDIM    11008

#define BM 128
#define BN 128
#define BK 64
#define NT (KDIM / BK)               // 64 K-tiles
#define ABYTES (BM * BK)             // 8192
#define BBYTES (BN * BK)             // 8192
#define BUF_BYTES (ABYTES + BBYTES)  // 16384
#define A_OFF 0
#define B_OFF ABYTES

typedef __attribute__((ext_vector_type(4))) int i32x4;

typedef const __attribute__((address_space(1))) char glob_char;
typedef __attribute__((address_space(3))) char lds_char;

__device__ __forceinline__ unsigned pack4(i32x4 v) {
  return  ((unsigned)v.x & 0xFFu)
        | (((unsigned)v.y & 0xFFu) << 8)
        | (((unsigned)v.z & 0xFFu) << 16)
        | (((unsigned)v.w)         << 24);
}

__global__ __launch_bounds__(256) void convert_i32_i8(const int* __restrict__ src,
                                                      unsigned* __restrict__ dst,
                                                      int n4) {
  int idx = blockIdx.x * 256 + threadIdx.x;
  if (idx >= n4) return;
  i32x4 v = ((const i32x4*)src)[idx];
  dst[idx] = pack4(v);
}

// C[2048][11008] = A[2048][4096] * W[11008][4096]^T via mfma_i32_16x16x64_i8.
// TAIL FIX (R6): grid 16x86=1376 blocks of 128x128, 48 KB LDS + <=170 regs
// -> 3 blocks/CU resident (capacity 768) -> 2 rounds, ~10% idle (vs the
// 688-grid/2-resident configs' 43/32 = 1.34 rounds = ~33% idle that pinned
// R1-R5 at MfmaUtil ~35%).
// 4 waves (2m x 2n), per-wave 64x64 as 4x4 frags; 2 phases x 8 MFMA per KT;
// 3 rotating LDS buffers, depth-2 prefetch, ONE counted vmcnt(4) per KT.
// Slot swizzle (R0/R2/R4/R5-validated, 0 conflicts): within each 64B row,
// physical 16B slot p holds logical slot p ^ ((row>>1)&3); applied on the
// global SOURCE for global_load_lds (linear dest) and on the ds_read addr.
__global__ __launch_bounds__(256, 3) void ternary_gemm(const char* __restrict__ A8,
                                                       const char* __restrict__ B8,
                                                       const float* __restrict__ scale,
                                                       const float* __restrict__ bias,
                                                       float* __restrict__ out) {
  __shared__ char lds[3 * BUF_BYTES];   // 49152 B -> 3 blocks/CU

  const int tid  = threadIdx.x;
  const int wid  = tid >> 6;
  const int lane = tid & 63;

  // XCD-aware swizzle; gridDim.x = 1376, 1376 % 8 == 0 -> bijective
  const int nwg = gridDim.x;
  const int cpx = nwg >> 3;             // 172
  const int wg  = (blockIdx.x & 7) * cpx + (blockIdx.x >> 3);
  const int mt = wg & 15;               // consecutive wg share the N-panel
  const int nt = wg >> 4;               // 0..85
  const int arow0 = mt * BM;
  const int brow0 = nt * BN;

  const int wr = wid >> 1;              // 0..1 : 64-row half
  const int wc = wid & 1;               // 0..1 : 64-col half
  const int rsub = lane & 15;
  const int sgrp = lane >> 4;           // k-slot 0..3

  // staging: 256 thr x 16B = 4KB/round = 64 rows; A rounds 0-1, B rounds 0-1
  const int srow  = tid >> 2;           // 0..63
  const int sslot = (tid & 3) ^ ((srow >> 1) & 3);  // r*64 preserves row bits 1-2
  const char* gA0 = A8 + (size_t)(arow0      + srow) * KDIM + sslot * 16;
  const char* gA1 = A8 + (size_t)(arow0 + 64 + srow) * KDIM + sslot * 16;
  const char* gB0 = B8 + (size_t)(brow0      + srow) * KDIM + sslot * 16;
  const char* gB1 = B8 + (size_t)(brow0 + 64 + srow) * KDIM + sslot * 16;

  auto stage = [&](const char* g, int bufo, int kt, int dsto) {
    __builtin_amdgcn_global_load_lds((glob_char*)(g + kt * BK),
        (lds_char*)(lds + bufo + dsto + wid * 1024), 16, 0, 0);
  };

  // loop-invariant fragment byte-offsets (0-conflict pattern)
  int offA[4], offB[4];
#pragma unroll
  for (int m = 0; m < 4; ++m) {
    const int row = wr * 64 + m * 16 + rsub;
    const int p   = sgrp ^ ((row >> 1) & 3);
    offA[m] = A_OFF + row * 64 + p * 16;
  }
#pragma unroll
  for (int n = 0; n < 4; ++n) {
    const int row = wc * 64 + n * 16 + rsub;
    const int p   = sgrp ^ ((row >> 1) & 3);
    offB[n] = B_OFF + row * 64 + p * 16;
  }

  i32x4 acc[4][4];
#pragma unroll
  for (int m = 0; m < 4; ++m)
#pragma unroll
    for (int n = 0; n < 4; ++n)
      acc[m][n] = (i32x4){0, 0, 0, 0};

  int cur = 0, nxt = BUF_BYTES, pf = 2 * BUF_BYTES;

  // prologue: stage tiles 0 and 1 in loop issue order (A0,A1,B0,B1)
  stage(gA0, cur, 0, A_OFF);  stage(gA1, cur, 0, A_OFF + 4096);
  stage(gB0, cur, 0, B_OFF);  stage(gB1, cur, 0, B_OFF + 4096);
  stage(gA0, nxt, 1, A_OFF);  stage(gA1, nxt, 1, A_OFF + 4096);
  stage(gB0, nxt, 1, B_OFF);  stage(gB1, nxt, 1, B_OFF + 4096);
  asm volatile("s_waitcnt vmcnt(4)" ::: "memory");   // tile 0 landed
  __builtin_amdgcn_s_barrier();

  for (int t = 0; t < NT; ++t) {
    const int kt2 = (t + 2 < NT) ? t + 2 : NT - 1;   // clamped dummy at tail

    i32x4 a0, a1, a2, a3, b0, b1, b2, b3;

    // ---- P0: read a0-3,b0,b1 ; stage A r0,r1 ; 8 MFMA (m x {0,1}) ----
    a0 = *(const i32x4*)(lds + cur + offA[0]);
    a1 = *(const i32x4*)(lds + cur + offA[1]);
    a2 = *(const i32x4*)(lds + cur + offA[2]);
    a3 = *(const i32x4*)(lds + cur + offA[3]);
    b0 = *(const i32x4*)(lds + cur + offB[0]);
    b1 = *(const i32x4*)(lds + cur + offB[1]);
    stage(gA0, pf, kt2, A_OFF);
    stage(gA1, pf, kt2, A_OFF + 4096);
    __builtin_amdgcn_s_barrier();
    asm volatile("s_waitcnt lgkmcnt(0)" ::: "memory");
    __builtin_amdgcn_sched_barrier(0);
    __builtin_amdgcn_s_setprio(1);
    acc[0][0] = __builtin_amdgcn_mfma_i32_16x16x64_i8(a0, b0, acc[0][0], 0, 0, 0);
    acc[1][0] = __builtin_amdgcn_mfma_i32_16x16x64_i8(a1, b0, acc[1][0], 0, 0, 0);
    acc[2][0] = __builtin_amdgcn_mfma_i32_16x16x64_i8(a2, b0, acc[2][0], 0, 0, 0);
    acc[3][0] = __builtin_amdgcn_mfma_i32_16x16x64_i8(a3, b0, acc[3][0], 0, 0, 0);
    acc[0][1] = __builtin_amdgcn_mfma_i32_16x16x64_i8(a0, b1, acc[0][1], 0, 0, 0);
    acc[1][1] = __builtin_amdgcn_mfma_i32_16x16x64_i8(a1, b1, acc[1][1], 0, 0, 0);
    acc[2][1] = __builtin_amdgcn_mfma_i32_16x16x64_i8(a2, b1, acc[2][1], 0, 0, 0);
    acc[3][1] = __builtin_amdgcn_mfma_i32_16x16x64_i8(a3, b1, acc[3][1], 0, 0, 0);
    __builtin_amdgcn_s_setprio(0);
    __builtin_amdgcn_s_barrier();

    // ---- P1: read b2,b3 ; stage B r0,r1 ; vmcnt(4) -> tile t+1 landed ;
    //          8 MFMA (m x {2,3}) ----
    b2 = *(const i32x4*)(lds + cur + offB[2]);
    b3 = *(const i32x4*)(lds + cur + offB[3]);
    stage(gB0, pf, kt2, B_OFF);
    stage(gB1, pf, kt2, B_OFF + 4096);
    asm volatile("s_waitcnt vmcnt(4)" ::: "memory");  // t+1's 4 retired; t+2's 4 in flight
    __builtin_amdgcn_s_barrier();
    asm volatile("s_waitcnt lgkmcnt(0)" ::: "memory");
    __builtin_amdgcn_sched_barrier(0);
    __builtin_amdgcn_s_setprio(1);
    acc[0][2] = __builtin_amdgcn_mfma_i32_16x16x64_i8(a0, b2, acc[0][2], 0, 0, 0);
    acc[1][2] = __builtin_amdgcn_mfma_i32_16x16x64_i8(a1, b2, acc[1][2], 0, 0, 0);
    acc[2][2] = __builtin_amdgcn_mfma_i32_16x16x64_i8(a2, b2, acc[2][2], 0, 0, 0);
    acc[3][2] = __builtin_amdgcn_mfma_i32_16x16x64_i8(a3, b2, acc[3][2], 0, 0, 0);
    acc[0][3] = __builtin_amdgcn_mfma_i32_16x16x64_i8(a0, b3, acc[0][3], 0, 0, 0);
    acc[1][3] = __builtin_amdgcn_mfma_i32_16x16x64_i8(a1, b3, acc[1][3], 0, 0, 0);
    acc[2][3] = __builtin_amdgcn_mfma_i32_16x16x64_i8(a2, b3, acc[2][3], 0, 0, 0);
    acc[3][3] = __builtin_amdgcn_mfma_i32_16x16x64_i8(a3, b3, acc[3][3], 0, 0, 0);
    __builtin_amdgcn_s_setprio(0);
    __builtin_amdgcn_s_barrier();   // all waves' cur-reads retired before cur is re-staged

    const int tb = cur; cur = nxt; nxt = pf; pf = tb;
  }

  // Epilogue (validated): C/D col = lane&15, row = (lane>>4)*4 + reg
  const int crow = sgrp * 4;
#pragma unroll
  for (int n = 0; n < 4; ++n) {
    const int col = brow0 + wc * 64 + n * 16 + rsub;
    const float sc = scale[col];
    const float bs = bias[col];
#pragma unroll
    for (int m = 0; m < 4; ++m) {
      const int r0 = arow0 + wr * 64 + m * 16 + crow;
#pragma unroll
      for (int j = 0; j < 4; ++j) {
        out[(size_t)(r0 + j) * NDIM + col] = (float)acc[m][n][j] * sc + bs;
      }
    }
  }
}

extern "C" void kernel_launch(void* const* d_in, const int* in_sizes, int n_in,
                              void* d_out, int out_size, void* d_ws, size_t ws_size,
                              hipStream_t stream) {
  const int*   input  = (const int*)d_in[0];     // [2048][4096] int32
  const int*   weight = (const int*)d_in[1];     // [11008][4096] int32 in {-1,0,1}
  const float* scale  = (const float*)d_in[2];   // [11008]
  const float* bias   = (const float*)d_in[3];   // [11008]
  float*       out    = (float*)d_out;           // [2048][11008] fp32

  const size_t needA = (size_t)BATCH * KDIM;     // 8 MB int8
  const size_t needB = (size_t)NDIM * KDIM;      // 44 MB int8

  char* A8 = (char*)d_ws;
  char* B8 = A8 + needA;
  const int nA4 = (int)(needA / 4);
  const int nB4 = (int)(needB / 4);
  convert_i32_i8<<<(nA4 + 255) / 256, 256, 0, stream>>>(input, (unsigned*)A8, nA4);
  convert_i32_i8<<<(nB4 + 255) / 256, 256, 0, stream>>>(weight, (unsigned*)B8, nB4);

  const dim3 grid((BATCH / BM) * (NDIM / BN));   // 16 * 86 = 1376
  const dim3 block(256);
  ternary_gemm<<<grid, block, 0, stream>>>(A8, B8, scale, bias, out);
  (void)ws_size; (void)n_in; (void)in_sizes; (void)out_size;
}

// Round 7
// 150.062 us; speedup vs baseline: 1.1603x; 1.1603x over previous
//
#include <hip/hip_runtime.h>
#include <stdint.h>

#define BATCH   2048
#define KDIM    4096
#define NDIM    11008

#define BM 128
#define BN 128
#define BK 128
#define NT (KDIM / BK)               // 32 K-tiles
#define ABYTES (BM * BK)             // 16384
#define BBYTES (BN * BK)             // 16384
#define BUF_BYTES (ABYTES + BBYTES)  // 32768
#define A_OFF 0
#define B_OFF ABYTES

typedef __attribute__((ext_vector_type(4))) int i32x4;

typedef const __attribute__((address_space(1))) char glob_char;
typedef __attribute__((address_space(3))) char lds_char;

__device__ __forceinline__ unsigned pack4(i32x4 v) {
  return  ((unsigned)v.x & 0xFFu)
        | (((unsigned)v.y & 0xFFu) << 8)
        | (((unsigned)v.z & 0xFFu) << 16)
        | (((unsigned)v.w)         << 24);
}

__global__ __launch_bounds__(256) void convert_i32_i8(const int* __restrict__ src,
                                                      unsigned* __restrict__ dst,
                                                      int n4) {
  int idx = blockIdx.x * 256 + threadIdx.x;
  if (idx >= n4) return;
  i32x4 v = ((const i32x4*)src)[idx];
  dst[idx] = pack4(v);
}

// C[2048][11008] = A[2048][4096] * W[11008][4096]^T via mfma_i32_16x16x64_i8.
// R7: 128x128 tile, BK=128, TRUE double buffer (2 x 32KB = 64KB -> 2 blk/CU,
// grid 1376 -> 3 rounds of 512, tail waste 10.4% vs R5's 33%).
// BARRIER-FREE phases: in-iter reads hit `cur`, staging writes hit `nxt`
// (disjoint) -> no inter-phase barriers needed. ONE vmcnt(0)+s_barrier per
// KT128 = 32 MFMA/wave between barriers (4x R5 cadence). ds_reads complete
// before each wave's barrier arrival (their MFMA consumers already ran).
// NO manual lgkmcnt / sched_barrier (R6 lesson: they serialize reads the
// compiler pipelines itself).
// Swizzle (8 slots of 16B per 128B row): physical slot = logical ^ (row&7);
// applied on global SOURCE (global_load_lds dest linear) and ds_read addr;
// per b128 read: 16 lanes spread over all 8 slot-groups (2 each) = full
// 32-bank width.
__global__ __launch_bounds__(256, 2) void ternary_gemm(const char* __restrict__ A8,
                                                       const char* __restrict__ B8,
                                                       const float* __restrict__ scale,
                                                       const float* __restrict__ bias,
                                                       float* __restrict__ out) {
  __shared__ char lds[2 * BUF_BYTES];   // 65536 B -> 2 blocks/CU

  const int tid  = threadIdx.x;
  const int wid  = tid >> 6;
  const int lane = tid & 63;

  // XCD-aware swizzle; gridDim.x = 1376, 1376 % 8 == 0 -> bijective
  const int nwg = gridDim.x;
  const int cpx = nwg >> 3;             // 172
  const int wg  = (blockIdx.x & 7) * cpx + (blockIdx.x >> 3);
  const int mt = wg & 15;               // consecutive wg share the N-panel
  const int nt = wg >> 4;               // 0..85
  const int arow0 = mt * BM;
  const int brow0 = nt * BN;

  const int wr = wid >> 1;              // 0..1 : 64-row half
  const int wc = wid & 1;               // 0..1 : 64-col half
  const int rsub = lane & 15;
  const int sgrp = lane >> 4;           // k-slot-in-64 (16 i8 each)

  // staging: 256 thr x 16B = 4KB/round = 32 rows of 128B; 4 rounds per matrix
  const int srow  = tid >> 3;           // 0..31 (row low bits, invariant mod 8 across rounds)
  const int sslot = (tid & 7) ^ (srow & 7);
  const char* gA[4];
  const char* gB[4];
#pragma unroll
  for (int r = 0; r < 4; ++r) {
    gA[r] = A8 + (size_t)(arow0 + r * 32 + srow) * KDIM + sslot * 16;
    gB[r] = B8 + (size_t)(brow0 + r * 32 + srow) * KDIM + sslot * 16;
  }

  auto stage = [&](const char* g, int bufo, int dsto) {
    __builtin_amdgcn_global_load_lds((glob_char*)g,
        (lds_char*)(lds + bufo + dsto + wid * 1024), 16, 0, 0);
  };

  // loop-invariant fragment byte-offsets: row*128 + phys_slot*16,
  // phys = (ksub*4 + sgrp) ^ (row & 7)
  int offA[4][2], offB[4][2];
#pragma unroll
  for (int m = 0; m < 4; ++m) {
    const int row = wr * 64 + m * 16 + rsub;
#pragma unroll
    for (int ks = 0; ks < 2; ++ks) {
      const int p = (ks * 4 + sgrp) ^ (row & 7);
      offA[m][ks] = A_OFF + row * 128 + p * 16;
    }
  }
#pragma unroll
  for (int n = 0; n < 4; ++n) {
    const int row = wc * 64 + n * 16 + rsub;
#pragma unroll
    for (int ks = 0; ks < 2; ++ks) {
      const int p = (ks * 4 + sgrp) ^ (row & 7);
      offB[n][ks] = B_OFF + row * 128 + p * 16;
    }
  }

  i32x4 acc[4][4];
#pragma unroll
  for (int m = 0; m < 4; ++m)
#pragma unroll
    for (int n = 0; n < 4; ++n)
      acc[m][n] = (i32x4){0, 0, 0, 0};

  int cur = 0, nxt = BUF_BYTES;

  // prologue: stage tile 0 into cur, drain, barrier
#pragma unroll
  for (int r = 0; r < 4; ++r) stage(gA[r], cur, A_OFF + r * 4096);
#pragma unroll
  for (int r = 0; r < 4; ++r) stage(gB[r], cur, B_OFF + r * 4096);
  asm volatile("s_waitcnt vmcnt(0)" ::: "memory");
  __builtin_amdgcn_s_barrier();

  for (int t = 0; t < NT; ++t) {
    const int ktn = ((t + 1 < NT) ? t + 1 : NT - 1) * BK;  // clamped tail re-stage

    // issue next tile's 8 staging loads first (earliest HBM start), into nxt
#pragma unroll
    for (int r = 0; r < 4; ++r) stage(gA[r] + ktn, nxt, A_OFF + r * 4096);
#pragma unroll
    for (int r = 0; r < 4; ++r) stage(gB[r] + ktn, nxt, B_OFF + r * 4096);

    // k-sub 0: read 8 frags from cur, 16 MFMA
    {
      i32x4 a0 = *(const i32x4*)(lds + cur + offA[0][0]);
      i32x4 a1 = *(const i32x4*)(lds + cur + offA[1][0]);
      i32x4 a2 = *(const i32x4*)(lds + cur + offA[2][0]);
      i32x4 a3 = *(const i32x4*)(lds + cur + offA[3][0]);
      i32x4 b0 = *(const i32x4*)(lds + cur + offB[0][0]);
      i32x4 b1 = *(const i32x4*)(lds + cur + offB[1][0]);
      i32x4 b2 = *(const i32x4*)(lds + cur + offB[2][0]);
      i32x4 b3 = *(const i32x4*)(lds + cur + offB[3][0]);
      __builtin_amdgcn_s_setprio(1);
      acc[0][0] = __builtin_amdgcn_mfma_i32_16x16x64_i8(a0, b0, acc[0][0], 0, 0, 0);
      acc[1][0] = __builtin_amdgcn_mfma_i32_16x16x64_i8(a1, b0, acc[1][0], 0, 0, 0);
      acc[2][0] = __builtin_amdgcn_mfma_i32_16x16x64_i8(a2, b0, acc[2][0], 0, 0, 0);
      acc[3][0] = __builtin_amdgcn_mfma_i32_16x16x64_i8(a3, b0, acc[3][0], 0, 0, 0);
      acc[0][1] = __builtin_amdgcn_mfma_i32_16x16x64_i8(a0, b1, acc[0][1], 0, 0, 0);
      acc[1][1] = __builtin_amdgcn_mfma_i32_16x16x64_i8(a1, b1, acc[1][1], 0, 0, 0);
      acc[2][1] = __builtin_amdgcn_mfma_i32_16x16x64_i8(a2, b1, acc[2][1], 0, 0, 0);
      acc[3][1] = __builtin_amdgcn_mfma_i32_16x16x64_i8(a3, b1, acc[3][1], 0, 0, 0);
      acc[0][2] = __builtin_amdgcn_mfma_i32_16x16x64_i8(a0, b2, acc[0][2], 0, 0, 0);
      acc[1][2] = __builtin_amdgcn_mfma_i32_16x16x64_i8(a1, b2, acc[1][2], 0, 0, 0);
      acc[2][2] = __builtin_amdgcn_mfma_i32_16x16x64_i8(a2, b2, acc[2][2], 0, 0, 0);
      acc[3][2] = __builtin_amdgcn_mfma_i32_16x16x64_i8(a3, b2, acc[3][2], 0, 0, 0);
      acc[0][3] = __builtin_amdgcn_mfma_i32_16x16x64_i8(a0, b3, acc[0][3], 0, 0, 0);
      acc[1][3] = __builtin_amdgcn_mfma_i32_16x16x64_i8(a1, b3, acc[1][3], 0, 0, 0);
      acc[2][3] = __builtin_amdgcn_mfma_i32_16x16x64_i8(a2, b3, acc[2][3], 0, 0, 0);
      acc[3][3] = __builtin_amdgcn_mfma_i32_16x16x64_i8(a3, b3, acc[3][3], 0, 0, 0);
      __builtin_amdgcn_s_setprio(0);
    }

    // k-sub 1: read 8 frags from cur, 16 MFMA
    {
      i32x4 a0 = *(const i32x4*)(lds + cur + offA[0][1]);
      i32x4 a1 = *(const i32x4*)(lds + cur + offA[1][1]);
      i32x4 a2 = *(const i32x4*)(lds + cur + offA[2][1]);
      i32x4 a3 = *(const i32x4*)(lds + cur + offA[3][1]);
      i32x4 b0 = *(const i32x4*)(lds + cur + offB[0][1]);
      i32x4 b1 = *(const i32x4*)(lds + cur + offB[1][1]);
      i32x4 b2 = *(const i32x4*)(lds + cur + offB[2][1]);
      i32x4 b3 = *(const i32x4*)(lds + cur + offB[3][1]);
      __builtin_amdgcn_s_setprio(1);
      acc[0][0] = __builtin_amdgcn_mfma_i32_16x16x64_i8(a0, b0, acc[0][0], 0, 0, 0);
      acc[1][0] = __builtin_amdgcn_mfma_i32_16x16x64_i8(a1, b0, acc[1][0], 0, 0, 0);
      acc[2][0] = __builtin_amdgcn_mfma_i32_16x16x64_i8(a2, b0, acc[2][0], 0, 0, 0);
      acc[3][0] = __builtin_amdgcn_mfma_i32_16x16x64_i8(a3, b0, acc[3][0], 0, 0, 0);
      acc[0][1] = __builtin_amdgcn_mfma_i32_16x16x64_i8(a0, b1, acc[0][1], 0, 0, 0);
      acc[1][1] = __builtin_amdgcn_mfma_i32_16x16x64_i8(a1, b1, acc[1][1], 0, 0, 0);
      acc[2][1] = __builtin_amdgcn_mfma_i32_16x16x64_i8(a2, b1, acc[2][1], 0, 0, 0);
      acc[3][1] = __builtin_amdgcn_mfma_i32_16x16x64_i8(a3, b1, acc[3][1], 0, 0, 0);
      acc[0][2] = __builtin_amdgcn_mfma_i32_16x16x64_i8(a0, b2, acc[0][2], 0, 0, 0);
      acc[1][2] = __builtin_amdgcn_mfma_i32_16x16x64_i8(a1, b2, acc[1][2], 0, 0, 0);
      acc[2][2] = __builtin_amdgcn_mfma_i32_16x16x64_i8(a2, b2, acc[2][2], 0, 0, 0);
      acc[3][2] = __builtin_amdgcn_mfma_i32_16x16x64_i8(a3, b2, acc[3][2], 0, 0, 0);
      acc[0][3] = __builtin_amdgcn_mfma_i32_16x16x64_i8(a0, b3, acc[0][3], 0, 0, 0);
      acc[1][3] = __builtin_amdgcn_mfma_i32_16x16x64_i8(a1, b3, acc[1][3], 0, 0, 0);
      acc[2][3] = __builtin_amdgcn_mfma_i32_16x16x64_i8(a2, b3, acc[2][3], 0, 0, 0);
      acc[3][3] = __builtin_amdgcn_mfma_i32_16x16x64_i8(a3, b3, acc[3][3], 0, 0, 0);
      __builtin_amdgcn_s_setprio(0);
    }

    // next tile landed; make staged data + buffer retirement visible block-wide
    asm volatile("s_waitcnt vmcnt(0)" ::: "memory");
    __builtin_amdgcn_s_barrier();

    const int tb = cur; cur = nxt; nxt = tb;
  }

  // Epilogue (validated R1-R6): C/D col = lane&15, row = (lane>>4)*4 + reg
  const int crow = sgrp * 4;
#pragma unroll
  for (int n = 0; n < 4; ++n) {
    const int col = brow0 + wc * 64 + n * 16 + rsub;
    const float sc = scale[col];
    const float bs = bias[col];
#pragma unroll
    for (int m = 0; m < 4; ++m) {
      const int r0 = arow0 + wr * 64 + m * 16 + crow;
#pragma unroll
      for (int j = 0; j < 4; ++j) {
        out[(size_t)(r0 + j) * NDIM + col] = (float)acc[m][n][j] * sc + bs;
      }
    }
  }
}

extern "C" void kernel_launch(void* const* d_in, const int* in_sizes, int n_in,
                              void* d_out, int out_size, void* d_ws, size_t ws_size,
                              hipStream_t stream) {
  const int*   input  = (const int*)d_in[0];     // [2048][4096] int32
  const int*   weight = (const int*)d_in[1];     // [11008][4096] int32 in {-1,0,1}
  const float* scale  = (const float*)d_in[2];   // [11008]
  const float* bias   = (const float*)d_in[3];   // [11008]
  float*       out    = (float*)d_out;           // [2048][11008] fp32

  const size_t needA = (size_t)BATCH * KDIM;     // 8 MB int8
  const size_t needB = (size_t)NDIM * KDIM;      // 44 MB int8

  char* A8 = (char*)d_ws;
  char* B8 = A8 + needA;
  const int nA4 = (int)(needA / 4);
  const int nB4 = (int)(needB / 4);
  convert_i32_i8<<<(nA4 + 255) / 256, 256, 0, stream>>>(input, (unsigned*)A8, nA4);
  convert_i32_i8<<<(nB4 + 255) / 256, 256, 0, stream>>>(weight, (unsigned*)B8, nB4);

  const dim3 grid((BATCH / BM) * (NDIM / BN));   // 16 * 86 = 1376
  const dim3 block(256);
  ternary_gemm<<<grid, block, 0, stream>>>(A8, B8, scale, bias, out);
  (void)ws_size; (void)n_in; (void)in_sizes; (void)out_size;
}